// Round 7
// baseline (282.949 us; speedup 1.0000x reference)
//
#include <hip/hip_runtime.h>

// B=16, C=256, L=2048 -> flat A: N=32768 rows x D=256; K=2048 codewords.
// Outputs (f32, concat): quantized[8388608], indices[32768], loss[1].
// d(n,k) = ||e_k||^2 - 2 x.e ; GEMM via split-bf16 3-pass MFMA; rows with
// top-2 gap < D2 skipped in main and finalized exactly (fp32) by rescore.
// Operands pre-swizzled in ws to the MFMA frag image: 16B cell = 8 bf16
// (k-octet), layout [chunk][q=0..3][lane16]*16B -> lane-linear reads.
//
// R7: main gets an explicit one-stage B register double-buffer (named bufs,
// macro-rotated parity -> static indexing, no scratch). R6 showed the matrix
// pipe idle ~55%: all 4 waves/SIMD stall together on the ~250cyc L2 latency
// at each stage top. Prefetching B(s+1) during MFMA(s) makes load-to-use
// distance ~466 cyc > latency. +32 VGPR (92+32acc=124, still 4/SIMD).
// setprio(1) around MFMA cluster (independent-wave regime). Geometry = R6.

#define ZE_CL   (256 * 2048)
#define NROWS   32768
#define KC      2048
#define DD      256
#define IDX_OFF 8388608
#define LOSS_OFF (8388608 + 32768)
#define D2 8e-3f

typedef __bf16 bf16x4 __attribute__((ext_vector_type(4)));
typedef __bf16 bf16x8 __attribute__((ext_vector_type(8)));
typedef float  f32x4  __attribute__((ext_vector_type(4)));

// ws layout (bytes)
#define EN_OFF  0u
#define EH_OFF  8192u
#define EL_OFF  (EH_OFF + 1048576u)
#define AH_OFF  (EL_OFF + 1048576u)
#define AL_OFF  (AH_OFF + 16777216u)
#define CNT_OFF (AL_OFF + 16777216u)
#define LST_OFF (CNT_OFF + 16u)
#define WS_NEED (LST_OFF + 131072u)

static __device__ inline void gld_lds16(const void* g, void* l) {
    __builtin_amdgcn_global_load_lds(
        (const __attribute__((address_space(1))) void*)g,
        (__attribute__((address_space(3))) void*)l, 16, 0, 0);
}

// ---------------- fused prep: transpose/split + emb prep + zeroing ----------
// blocks [0,2048): z_e transpose + A + Ah/Al swizzle.
// blocks [2048,2112): emb -> enorm + Eh/El swizzle (32 cols/block, 8 thr/col).
// block 2048 additionally zeroes rcount and the loss accumulator.
__global__ void vq_prep_all(const float* __restrict__ ze, const float* __restrict__ emb,
                            float* __restrict__ out, float* __restrict__ enorm,
                            __bf16* __restrict__ Eh, __bf16* __restrict__ El,
                            __bf16* __restrict__ Ah, __bf16* __restrict__ Al,
                            int* __restrict__ rcount) {
    __shared__ float T[16 * 272];
    int tid = threadIdx.x;
    int bid = blockIdx.x;

    if (bid >= 2048) {
        int pb = bid - 2048;
        if (pb == 0) {
            if (tid < 4) rcount[tid] = 0;
            if (tid == 4) out[LOSS_OFF] = 0.f;
        }
        int col = pb * 32 + (tid >> 3);
        int ch  = tid & 7;
        const float4* src = (const float4*)(emb + (size_t)col * DD);
        int t8 = col >> 8, g = (col >> 4) & 15, c = col & 15;
        float s = 0.f;
#pragma unroll
        for (int q = 0; q < 4; ++q) {
            float4 v0 = src[ch * 8 + q * 2];
            float4 v1 = src[ch * 8 + q * 2 + 1];
            float f[8] = {v0.x, v0.y, v0.z, v0.w, v1.x, v1.y, v1.z, v1.w};
            bf16x8 h, l;
#pragma unroll
            for (int j = 0; j < 8; ++j) {
                h[j] = (__bf16)f[j];
                l[j] = (__bf16)(f[j] - (float)h[j]);
                s += f[j] * f[j];
            }
            size_t off = ((size_t)(t8 * 8 + ch) * 16384) + (size_t)(g * 1024 + q * 256 + c * 16);
            *(bf16x8*)((char*)Eh + off) = h;
            *(bf16x8*)((char*)El + off) = l;
        }
        s += __shfl_xor(s, 1, 64);
        s += __shfl_xor(s, 2, 64);
        s += __shfl_xor(s, 4, 64);
        if (ch == 0) enorm[col] = s;
        return;
    }

    // transpose path
    float* A = out;
    int m  = bid & 15;
    int lt = bid >> 4;
    int l0 = lt * 16;
#pragma unroll
    for (int it = 0; it < 4; ++it) {
        int p   = tid + it * 256;
        int b   = p >> 6;
        int clo = (p >> 2) & 15;
        int l4  = p & 3;
        const float* g = ze + (size_t)b * ZE_CL + (size_t)(m * 16 + clo) * 2048 + l0 + 4 * l4;
        float4 v = *(const float4*)g;
        int jp = 17 * clo + b;
        T[(4 * l4 + 0) * 272 + jp] = v.x;
        T[(4 * l4 + 1) * 272 + jp] = v.y;
        T[(4 * l4 + 2) * 272 + jp] = v.z;
        T[(4 * l4 + 3) * 272 + jp] = v.w;
    }
    __syncthreads();
#pragma unroll
    for (int it = 0; it < 4; ++it) {
        int p  = tid + it * 256;
        int ll = p >> 6;
        int c4 = p & 63;
        int j0 = 4 * c4;
        int base = ll * 272 + 17 * (j0 >> 4) + (j0 & 15);
        float4 v;
        v.x = T[base + 0]; v.y = T[base + 1]; v.z = T[base + 2]; v.w = T[base + 3];
        int n = (l0 + ll) * 16 + m;
        *(float4*)(A + (size_t)n * DD + j0) = v;
        {
            float a0 = -2.f * v.x, a1 = -2.f * v.y, a2 = -2.f * v.z, a3 = -2.f * v.w;
            bf16x4 h, l;
            h[0] = (__bf16)a0; l[0] = (__bf16)(a0 - (float)h[0]);
            h[1] = (__bf16)a1; l[1] = (__bf16)(a1 - (float)h[1]);
            h[2] = (__bf16)a2; l[2] = (__bf16)(a2 - (float)h[2]);
            h[3] = (__bf16)a3; l[3] = (__bf16)(a3 - (float)h[3]);
            int bn = n >> 6, mi = (n >> 4) & 3, r = n & 15;
            int ch = j0 >> 5, q = (j0 >> 3) & 3, hb = (j0 & 7) * 2;
            size_t off = (size_t)bn * 32768 + (size_t)((mi * 8 + ch) * 1024 + q * 256 + r * 16 + hb);
            *(bf16x4*)((char*)Ah + off) = h;
            *(bf16x4*)((char*)Al + off) = l;
        }
    }
}

// One pipeline stage: ds-read A(CH), prefetch B(next) into NXT*, 3 MFMA
// passes on CUR*. Static buffer names -> no scratch (rule #20).
#define VQ_STAGE(CH, NBH, NBL, CURH, CURL, NXTH, NXTL, DO_PREF)                 \
    {                                                                           \
        bf16x8 ah[2], al[2];                                                    \
        _Pragma("unroll")                                                       \
        for (int mi = 0; mi < 2; ++mi) {                                        \
            size_t aoff = (size_t)((mi * 8 + (CH)) * 1024);                     \
            ah[mi] = *(const bf16x8*)(sAl16 + aoff);                            \
            al[mi] = *(const bf16x8*)(sAl16 + 16384 + aoff);                    \
        }                                                                       \
        if (DO_PREF) {                                                          \
            _Pragma("unroll")                                                   \
            for (int nj = 0; nj < 4; ++nj) {                                    \
                NXTH[nj] = *(const bf16x8*)((NBH) + nj * 1024);                  \
                NXTL[nj] = *(const bf16x8*)((NBL) + nj * 1024);                  \
            }                                                                   \
        }                                                                       \
        __builtin_amdgcn_s_setprio(1);                                          \
        _Pragma("unroll")                                                       \
        for (int mi = 0; mi < 2; ++mi)                                          \
            _Pragma("unroll")                                                   \
            for (int nj = 0; nj < 4; ++nj)                                      \
                acc[mi][nj] = __builtin_amdgcn_mfma_f32_16x16x32_bf16(ah[mi], CURH[nj], acc[mi][nj], 0, 0, 0); \
        _Pragma("unroll")                                                       \
        for (int mi = 0; mi < 2; ++mi)                                          \
            _Pragma("unroll")                                                   \
            for (int nj = 0; nj < 4; ++nj)                                      \
                acc[mi][nj] = __builtin_amdgcn_mfma_f32_16x16x32_bf16(ah[mi], CURL[nj], acc[mi][nj], 0, 0, 0); \
        _Pragma("unroll")                                                       \
        for (int mi = 0; mi < 2; ++mi)                                          \
            _Pragma("unroll")                                                   \
            for (int nj = 0; nj < 4; ++nj)                                      \
                acc[mi][nj] = __builtin_amdgcn_mfma_f32_16x16x32_bf16(al[mi], CURH[nj], acc[mi][nj], 0, 0, 0); \
        __builtin_amdgcn_s_setprio(0);                                          \
    }

// ---------------- MFMA distance + top-2 argmin + fused epilogue ----------------
// 1024 blocks x 4 waves (256 thr). Block: 32 rows x 2048 cols (8 passes of 256).
// Wave: 32 rows x 64 cols via 2x4 frags of mfma_f32_16x16x32_bf16.
// A (32 KB) in LDS after one-time fill; B streams from global (E, L2-resident)
// through a one-stage register double-buffer. No in-loop barriers.
__global__ __launch_bounds__(256, 2) void vq_main_mfma(
    const __bf16* __restrict__ Ah, const __bf16* __restrict__ Al,
    const __bf16* __restrict__ Eh, const __bf16* __restrict__ El,
    const float* __restrict__ enorm, const float* __restrict__ emb,
    float* out, int* __restrict__ rcount, int* __restrict__ rlist)
{
    __shared__ __align__(16) char sA[32768];     // Ah slice [0,16K), Al slice [16K,32K)
    __shared__ float sRv[128], sR2[128];
    __shared__ int   sRi[128];
    __shared__ int   sIdx[32], sFlag[32];
    __shared__ float wsum[4];

    const int tid  = threadIdx.x;
    const int wv   = tid >> 6;        // 0..3
    const int lane = tid & 63;
    const int l15  = lane & 15;
    const int quad = lane >> 4;
    const int n0   = blockIdx.x * 32;
    const int bn   = blockIdx.x >> 1;          // 64-row image block
    const int miB  = (blockIdx.x & 1) * 2;     // which half (mi planes 0-1 / 2-3)

    // one-time A -> LDS fill: 16KB hi + 16KB lo (wave-uniform base + lane*16)
    {
        const char* srcH = (const char*)Ah + (size_t)bn * 32768 + (size_t)miB * 8192;
        const char* srcL = (const char*)Al + (size_t)bn * 32768 + (size_t)miB * 8192;
#pragma unroll
        for (int it = 0; it < 4; ++it) {
            int off = (it * 4 + wv) * 1024;
            gld_lds16(srcH + off + lane * 16, sA + off);
            gld_lds16(srcL + off + lane * 16, sA + 16384 + off);
        }
    }

    // wave's B base: cells (wv*4+nj) of each 16KB ch-chunk, lane-linear
    const char* EhW = (const char*)Eh + (size_t)(wv * 4) * 1024 + (size_t)lane * 16;
    const char* ElW = (const char*)El + (size_t)(wv * 4) * 1024 + (size_t)lane * 16;
    const char* sAl16 = sA + (size_t)lane * 16;

    float v1[8], v2[8]; int i1[8];
#pragma unroll
    for (int s = 0; s < 8; ++s) { v1[s] = 3.4e38f; v2[s] = 3.4e38f; i1[s] = 0; }

    // prologue: B(nt=0, ch=0) into buf0 (completes under the A-fill barrier)
    bf16x8 b0h[4], b0l[4], b1h[4], b1l[4];
#pragma unroll
    for (int nj = 0; nj < 4; ++nj) {
        b0h[nj] = *(const bf16x8*)(EhW + nj * 1024);
        b0l[nj] = *(const bf16x8*)(ElW + nj * 1024);
    }

    __syncthreads();   // A fill complete (drains vmcnt for global_load_lds)

    for (int nt = 0; nt < 8; ++nt) {
        const char* EhT = EhW + (size_t)nt * 131072;
        const char* ElT = ElW + (size_t)nt * 131072;
        f32x4 acc[2][4];
#pragma unroll
        for (int a = 0; a < 2; ++a)
#pragma unroll
            for (int b = 0; b < 4; ++b) acc[a][b] = (f32x4){0.f, 0.f, 0.f, 0.f};

        // 8 stages, parity-rotated register double-buffer; stage 7 prefetches
        // (nt+1, ch=0) so the buffer is warm across the nt boundary.
        VQ_STAGE(0, EhT + 1 * 16384, ElT + 1 * 16384, b0h, b0l, b1h, b1l, 1)
        VQ_STAGE(1, EhT + 2 * 16384, ElT + 2 * 16384, b1h, b1l, b0h, b0l, 1)
        VQ_STAGE(2, EhT + 3 * 16384, ElT + 3 * 16384, b0h, b0l, b1h, b1l, 1)
        VQ_STAGE(3, EhT + 4 * 16384, ElT + 4 * 16384, b1h, b1l, b0h, b0l, 1)
        VQ_STAGE(4, EhT + 5 * 16384, ElT + 5 * 16384, b0h, b0l, b1h, b1l, 1)
        VQ_STAGE(5, EhT + 6 * 16384, ElT + 6 * 16384, b1h, b1l, b0h, b0l, 1)
        VQ_STAGE(6, EhT + 7 * 16384, ElT + 7 * 16384, b0h, b0l, b1h, b1l, 1)
        VQ_STAGE(7, EhT + 131072,    ElT + 131072,    b1h, b1l, b0h, b0l, (nt < 7))

        // fold N-pass into running top-2 (branchless; overlaps prefetched loads)
#pragma unroll
        for (int nj = 0; nj < 4; ++nj) {
            int k = nt * 256 + wv * 64 + nj * 16 + l15;
            float en = enorm[k];
#pragma unroll
            for (int mi = 0; mi < 2; ++mi)
#pragma unroll
                for (int r = 0; r < 4; ++r) {
                    float d = acc[mi][nj][r] + en;
                    int slot = mi * 4 + r;
                    float nv2 = fminf(v2[slot], fmaxf(v1[slot], d));
                    if (d < v1[slot]) i1[slot] = k;
                    v1[slot] = fminf(v1[slot], d);
                    v2[slot] = nv2;
                }
        }
    }

    // cross-lane top-2 merge over 16 lanes (rows fixed per quad)
#pragma unroll
    for (int slot = 0; slot < 8; ++slot) {
        float a1 = v1[slot], a2 = v2[slot];
        int ai = i1[slot];
#pragma unroll
        for (int m = 1; m < 16; m <<= 1) {
            float b1 = __shfl_xor(a1, m, 64);
            float b2 = __shfl_xor(a2, m, 64);
            int bi = __shfl_xor(ai, m, 64);
            float n2 = fminf(fminf(a2, b2), fmaxf(a1, b1));
            if (b1 < a1) ai = bi;
            a1 = fminf(a1, b1);
            a2 = n2;
        }
        if (l15 == 0) {
            int row = (slot >> 2) * 16 + quad * 4 + (slot & 3);   // 0..31
            sRv[row * 4 + wv] = a1;
            sR2[row * 4 + wv] = a2;
            sRi[row * 4 + wv] = ai;
        }
    }
    __syncthreads();
    if (tid < 32) {
        float a1 = sRv[tid * 4], a2 = sR2[tid * 4];
        int ai = sRi[tid * 4];
#pragma unroll
        for (int w2 = 1; w2 < 4; ++w2) {
            float b1 = sRv[tid * 4 + w2], b2 = sR2[tid * 4 + w2];
            int bi = sRi[tid * 4 + w2];
            float n2 = fminf(fminf(a2, b2), fmaxf(a1, b1));
            if (b1 < a1) ai = bi;
            a1 = fminf(a1, b1);
            a2 = n2;
        }
        int fg = (a2 - a1 < D2) ? 1 : 0;   // exact ties (gap 0) always flagged -> rescore
        sIdx[tid] = ai;
        sFlag[tid] = fg;
        out[IDX_OFF + n0 + tid] = (float)ai;
        if (fg) { int p = atomicAdd(rcount, 1); rlist[p] = n0 + tid; }
    }
    __syncthreads();

    // fused epilogue: quantize + loss for non-flagged rows (x fp32 still in out)
    float lacc = 0.f;
#pragma unroll
    for (int it = 0; it < 8; ++it) {
        int p = tid + it * 256;
        int r = p >> 6;             // 0..31, whole wave shares a row
        int c4 = p & 63;
        if (!sFlag[r]) {
            int k = sIdx[r];
            size_t off = (size_t)(n0 + r) * DD + 4 * c4;
            float4 q = *(const float4*)(emb + (size_t)k * DD + 4 * c4);
            float4 a = *(const float4*)(out + off);
            float dx = q.x - a.x, dy = q.y - a.y, dz = q.z - a.z, dw = q.w - a.w;
            lacc += dx * dx + dy * dy + dz * dz + dw * dw;
            *(float4*)(out + off) = q;
        }
    }
#pragma unroll
    for (int off = 32; off > 0; off >>= 1) lacc += __shfl_down(lacc, off, 64);
    if ((tid & 63) == 0) wsum[tid >> 6] = lacc;
    __syncthreads();
    if (tid == 0) {
        float bs = wsum[0] + wsum[1] + wsum[2] + wsum[3];
        atomicAdd(out + LOSS_OFF, bs * (1.25f / 8388608.0f));
    }
}

// ---------------- exact fp32 finalize of flagged rows ----------------
__global__ void vq_rescore(const float* __restrict__ emb, const float* __restrict__ enorm,
                           float* out, const int* __restrict__ rcount,
                           const int* __restrict__ rlist) {
    __shared__ float sX[256];
    __shared__ float sV[256];
    __shared__ int   sK[256];
    __shared__ float sP[256];
    int cnt = *rcount;
    int tid = threadIdx.x;
    for (int li = blockIdx.x; li < cnt; li += gridDim.x) {
        int row = rlist[li];
        __syncthreads();
        sX[tid] = out[(size_t)row * DD + tid];   // fp32 x (main skipped this row)
        __syncthreads();
        float bv = 3.4e38f; int bk = 0;
        for (int jj = 0; jj < 8; ++jj) {
            int k = jj * 256 + tid;   // ascending per thread: '<' keeps first
            const float4* e4 = (const float4*)(emb + (size_t)k * DD);
            float dot = 0.f;
#pragma unroll 8
            for (int d4 = 0; d4 < 64; ++d4) {
                float4 e = e4[d4];
                float4 x = *(const float4*)(sX + d4 * 4);
                dot += x.x * e.x + x.y * e.y + x.z * e.z + x.w * e.w;
            }
            float s = enorm[k] - 2.f * dot;
            if (s < bv) { bv = s; bk = k; }
        }
        sV[tid] = bv; sK[tid] = bk;
        __syncthreads();
#pragma unroll
        for (int s = 128; s > 0; s >>= 1) {
            if (tid < s) {
                float vo = sV[tid + s]; int ko = sK[tid + s];
                if (vo < sV[tid] || (vo == sV[tid] && ko < sK[tid])) { sV[tid] = vo; sK[tid] = ko; }
            }
            __syncthreads();
        }
        int k = sK[0];
        float x = sX[tid];
        float q = emb[(size_t)k * DD + tid];
        out[(size_t)row * DD + tid] = q;
        float d = q - x;
        sP[tid] = d * d;
        __syncthreads();
#pragma unroll
        for (int s = 128; s > 0; s >>= 1) {
            if (tid < s) sP[tid] += sP[tid + s];
            __syncthreads();
        }
        if (tid == 0) {
            out[IDX_OFF + row] = (float)k;
            atomicAdd(out + LOSS_OFF, sP[0] * (1.25f / 8388608.0f));
        }
    }
}

// ---------------- fallback path kernels (only if ws too small) ----------------
__global__ void vq_prep_emb(const float* __restrict__ emb, float* __restrict__ enorm,
                            __bf16* __restrict__ Eh, __bf16* __restrict__ El) {
    int tid = threadIdx.x;
    int col = blockIdx.x * 32 + (tid >> 3);
    int ch  = tid & 7;
    const float4* src = (const float4*)(emb + (size_t)col * DD);
    int t8 = col >> 8, g = (col >> 4) & 15, c = col & 15;
    float s = 0.f;
#pragma unroll
    for (int q = 0; q < 4; ++q) {
        float4 v0 = src[ch * 8 + q * 2];
        float4 v1 = src[ch * 8 + q * 2 + 1];
        float f[8] = {v0.x, v0.y, v0.z, v0.w, v1.x, v1.y, v1.z, v1.w};
        bf16x8 h, l;
#pragma unroll
        for (int j = 0; j < 8; ++j) {
            h[j] = (__bf16)f[j];
            l[j] = (__bf16)(f[j] - (float)h[j]);
            s += f[j] * f[j];
        }
        size_t off = ((size_t)(t8 * 8 + ch) * 16384) + (size_t)(g * 1024 + q * 256 + c * 16);
        *(bf16x8*)((char*)Eh + off) = h;
        *(bf16x8*)((char*)El + off) = l;
    }
    s += __shfl_xor(s, 1, 64);
    s += __shfl_xor(s, 2, 64);
    s += __shfl_xor(s, 4, 64);
    if (ch == 0) enorm[col] = s;
}

__global__ void vq_transpose_split(const float* __restrict__ ze, float* __restrict__ A,
                                   __bf16* __restrict__ Ah, __bf16* __restrict__ Al) {
    __shared__ float T[16 * 272];
    int tid = threadIdx.x;
    int m  = blockIdx.x & 15;
    int lt = blockIdx.x >> 4;
    int l0 = lt * 16;
#pragma unroll
    for (int it = 0; it < 4; ++it) {
        int p   = tid + it * 256;
        int b   = p >> 6;
        int clo = (p >> 2) & 15;
        int l4  = p & 3;
        const float* g = ze + (size_t)b * ZE_CL + (size_t)(m * 16 + clo) * 2048 + l0 + 4 * l4;
        float4 v = *(const float4*)g;
        int jp = 17 * clo + b;
        T[(4 * l4 + 0) * 272 + jp] = v.x;
        T[(4 * l4 + 1) * 272 + jp] = v.y;
        T[(4 * l4 + 2) * 272 + jp] = v.z;
        T[(4 * l4 + 3) * 272 + jp] = v.w;
    }
    __syncthreads();
#pragma unroll
    for (int it = 0; it < 4; ++it) {
        int p  = tid + it * 256;
        int ll = p >> 6;
        int c4 = p & 63;
        int j0 = 4 * c4;
        int base = ll * 272 + 17 * (j0 >> 4) + (j0 & 15);
        float4 v;
        v.x = T[base + 0]; v.y = T[base + 1]; v.z = T[base + 2]; v.w = T[base + 3];
        int n = (l0 + ll) * 16 + m;
        *(float4*)(A + (size_t)n * DD + j0) = v;
        if (Ah) {
            float a0 = -2.f * v.x, a1 = -2.f * v.y, a2 = -2.f * v.z, a3 = -2.f * v.w;
            bf16x4 h, l;
            h[0] = (__bf16)a0; l[0] = (__bf16)(a0 - (float)h[0]);
            h[1] = (__bf16)a1; l[1] = (__bf16)(a1 - (float)h[1]);
            h[2] = (__bf16)a2; l[2] = (__bf16)(a2 - (float)h[2]);
            h[3] = (__bf16)a3; l[3] = (__bf16)(a3 - (float)h[3]);
            int bn = n >> 6, mi = (n >> 4) & 3, r = n & 15;
            int ch = j0 >> 5, q = (j0 >> 3) & 3, hb = (j0 & 7) * 2;
            size_t off = (size_t)bn * 32768 + (size_t)((mi * 8 + ch) * 1024 + q * 256 + r * 16 + hb);
            *(bf16x4*)((char*)Ah + off) = h;
            *(bf16x4*)((char*)Al + off) = l;
        }
    }
}

__global__ __launch_bounds__(256, 2) void vq_main_f32(const float* __restrict__ emb,
                                                      const float* __restrict__ enorm,
                                                      float* out) {
    const int SA = 68, SE = 68;
    __shared__ float smem[64 * 68 + 64 * 68];
    __shared__ int   sIdx[64];
    __shared__ float wsum[4];
    float* sA = smem;
    float* sEb = smem + 64 * SA;
    float* redv = sEb;
    int*   redi = (int*)(sEb + 64 * 16);
    int tid = threadIdx.x;
    int n0 = blockIdx.x * 64;
    int rg = tid & 15;
    int kg = tid >> 4;
    float minv[4]; int mini[4];
#pragma unroll
    for (int i = 0; i < 4; ++i) { minv[i] = 3.4e38f; mini[i] = 0; }
    const float* A = out;
    for (int kt = 0; kt < KC / 64; ++kt) {
        int k0 = kt * 64;
        float acc[4][4];
#pragma unroll
        for (int i = 0; i < 4; ++i)
#pragma unroll
            for (int j = 0; j < 4; ++j) acc[i][j] = 0.f;
        for (int dc = 0; dc < 4; ++dc) {
            int d0 = dc * 64;
            __syncthreads();
#pragma unroll
            for (int it = 0; it < 4; ++it) {
                int p = tid + it * 256, r = p >> 4, c4 = p & 15;
                *(float4*)(sA + r * SA + 4 * c4) =
                    *(const float4*)(A + (size_t)(n0 + r) * DD + d0 + 4 * c4);
            }
#pragma unroll
            for (int it = 0; it < 4; ++it) {
                int p = tid + it * 256, r = p >> 4, c4 = p & 15;
                *(float4*)(sEb + r * SE + 4 * c4) =
                    *(const float4*)(emb + (size_t)(k0 + r) * DD + d0 + 4 * c4);
            }
            __syncthreads();
#pragma unroll
            for (int d4 = 0; d4 < 16; ++d4) {
                float4 av[4], ev[4];
#pragma unroll
                for (int i = 0; i < 4; ++i) av[i] = *(const float4*)(sA + (rg + 16 * i) * SA + 4 * d4);
#pragma unroll
                for (int j = 0; j < 4; ++j) ev[j] = *(const float4*)(sEb + (kg + 16 * j) * SE + 4 * d4);
#pragma unroll
                for (int i = 0; i < 4; ++i)
#pragma unroll
                    for (int j = 0; j < 4; ++j)
                        acc[i][j] += av[i].x * ev[j].x + av[i].y * ev[j].y +
                                     av[i].z * ev[j].z + av[i].w * ev[j].w;
            }
        }
#pragma unroll
        for (int j = 0; j < 4; ++j) {
            int k = k0 + kg + 16 * j;
            float en = enorm[k];
#pragma unroll
            for (int i = 0; i < 4; ++i) {
                float s = en - 2.f * acc[i][j];
                if (s < minv[i]) { minv[i] = s; mini[i] = k; }
            }
        }
    }
    __syncthreads();
#pragma unroll
    for (int i = 0; i < 4; ++i) {
        int r = rg + 16 * i;
        redv[r * 16 + kg] = minv[i];
        redi[r * 16 + kg] = mini[i];
    }
    __syncthreads();
    if (tid < 64) {
        float bv = redv[tid * 16]; int bi = redi[tid * 16];
        for (int t = 1; t < 16; ++t) {
            float v = redv[tid * 16 + t]; int ii = redi[tid * 16 + t];
            if (v < bv || (v == bv && ii < bi)) { bv = v; bi = ii; }
        }
        sIdx[tid] = bi;
        out[IDX_OFF + n0 + tid] = (float)bi;
    }
    __syncthreads();
    float lacc = 0.f;
#pragma unroll
    for (int it = 0; it < 16; ++it) {
        int p = tid + it * 256, r = p >> 6, c4 = p & 63;
        int k = sIdx[r];
        size_t off = (size_t)(n0 + r) * DD + 4 * c4;
        float4 q = *(const float4*)(emb + (size_t)k * DD + 4 * c4);
        float4 a = *(const float4*)(out + off);
        float dx = q.x - a.x, dy = q.y - a.y, dz = q.z - a.z, dw = q.w - a.w;
        lacc += dx * dx + dy * dy + dz * dz + dw * dw;
        *(float4*)(out + off) = q;
    }
#pragma unroll
    for (int off = 32; off > 0; off >>= 1) lacc += __shfl_down(lacc, off, 64);
    if ((tid & 63) == 0) wsum[tid >> 6] = lacc;
    __syncthreads();
    if (tid == 0) {
        float bs = wsum[0] + wsum[1] + wsum[2] + wsum[3];
        atomicAdd(out + LOSS_OFF, bs * (1.25f / 8388608.0f));
    }
}

extern "C" void kernel_launch(void* const* d_in, const int* in_sizes, int n_in,
                              void* d_out, int out_size, void* d_ws, size_t ws_size,
                              hipStream_t stream) {
    (void)in_sizes; (void)n_in; (void)out_size;
    const float* ze  = (const float*)d_in[0];
    const float* emb = (const float*)d_in[1];
    float* out = (float*)d_out;
    char*  ws  = (char*)d_ws;
    float* enorm = (float*)(ws + EN_OFF);

    if (ws_size >= (size_t)WS_NEED) {
        __bf16* Eh = (__bf16*)(ws + EH_OFF);
        __bf16* El = (__bf16*)(ws + EL_OFF);
        __bf16* Ah = (__bf16*)(ws + AH_OFF);
        __bf16* Al = (__bf16*)(ws + AL_OFF);
        int* rcount = (int*)(ws + CNT_OFF);
        int* rlist  = (int*)(ws + LST_OFF);
        vq_prep_all<<<2112, 256, 0, stream>>>(ze, emb, out, enorm, Eh, El, Ah, Al, rcount);
        vq_main_mfma<<<NROWS / 32, 256, 0, stream>>>(Ah, Al, Eh, El, enorm, emb, out, rcount, rlist);
        vq_rescore<<<512, 256, 0, stream>>>(emb, enorm, out, rcount, rlist);
    } else {
        // fallback: fp32 path (slow but correct)
        hipMemsetAsync((char*)d_out + (size_t)LOSS_OFF * 4, 0, 4, stream);
        vq_prep_emb<<<64, 256, 0, stream>>>(emb, enorm, (__bf16*)(ws + EH_OFF), (__bf16*)(ws + EH_OFF));
        vq_transpose_split<<<2048, 256, 0, stream>>>(ze, out, (__bf16*)0, (__bf16*)0);
        vq_main_f32<<<NROWS / 64, 256, 0, stream>>>(emb, enorm, out);
    }
}

// Round 8
// 276.432 us; speedup vs baseline: 1.0236x; 1.0236x over previous
//
#include <hip/hip_runtime.h>

// B=16, C=256, L=2048 -> flat A: N=32768 rows x D=256; K=2048 codewords.
// Outputs (f32, concat): quantized[8388608], indices[32768], loss[1].
// d(n,k) = ||e_k||^2 - 2 x.e ; GEMM via split-bf16 3-pass MFMA; rows with
// top-2 gap < D2 skipped in main and finalized exactly (fp32) by rescore.
// Operands pre-swizzled in ws to the MFMA frag image: 16B cell = 8 bf16
// (k-octet), layout [chunk][q=0..3][lane16]*16B -> lane-linear reads.
//
// R8: R7's register double-buffer reverted (VGPR 60->128 + scratch, occ
// 36->20%, main 109->125us). Back to R6's clean loop + ONE change: each
// block walks the E image in a rotated order (nt0=(bid>>3)&7,
// ch0=(bid>>6)&7). Previously all 1024 blocks streamed the SAME 32KB chunk
// simultaneously -> L2 bank hotspot (same-XCD CUs serialize on identical
// lines), the invariant matching MfmaUtil pinned at ~40% across R2-R7.
// Rotation spreads concurrent reads over the whole 2MB image.

#define ZE_CL   (256 * 2048)
#define NROWS   32768
#define KC      2048
#define DD      256
#define IDX_OFF 8388608
#define LOSS_OFF (8388608 + 32768)
#define D2 8e-3f

typedef __bf16 bf16x4 __attribute__((ext_vector_type(4)));
typedef __bf16 bf16x8 __attribute__((ext_vector_type(8)));
typedef float  f32x4  __attribute__((ext_vector_type(4)));

// ws layout (bytes)
#define EN_OFF  0u
#define EH_OFF  8192u
#define EL_OFF  (EH_OFF + 1048576u)
#define AH_OFF  (EL_OFF + 1048576u)
#define AL_OFF  (AH_OFF + 16777216u)
#define CNT_OFF (AL_OFF + 16777216u)
#define LST_OFF (CNT_OFF + 16u)
#define WS_NEED (LST_OFF + 131072u)

static __device__ inline void gld_lds16(const void* g, void* l) {
    __builtin_amdgcn_global_load_lds(
        (const __attribute__((address_space(1))) void*)g,
        (__attribute__((address_space(3))) void*)l, 16, 0, 0);
}

// ---------------- fused prep: transpose/split + emb prep + zeroing ----------
// blocks [0,2048): z_e transpose + A + Ah/Al swizzle.
// blocks [2048,2112): emb -> enorm + Eh/El swizzle (32 cols/block, 8 thr/col).
// block 2048 additionally zeroes rcount and the loss accumulator.
__global__ void vq_prep_all(const float* __restrict__ ze, const float* __restrict__ emb,
                            float* __restrict__ out, float* __restrict__ enorm,
                            __bf16* __restrict__ Eh, __bf16* __restrict__ El,
                            __bf16* __restrict__ Ah, __bf16* __restrict__ Al,
                            int* __restrict__ rcount) {
    __shared__ float T[16 * 272];
    int tid = threadIdx.x;
    int bid = blockIdx.x;

    if (bid >= 2048) {
        int pb = bid - 2048;
        if (pb == 0) {
            if (tid < 4) rcount[tid] = 0;
            if (tid == 4) out[LOSS_OFF] = 0.f;
        }
        int col = pb * 32 + (tid >> 3);
        int ch  = tid & 7;
        const float4* src = (const float4*)(emb + (size_t)col * DD);
        int t8 = col >> 8, g = (col >> 4) & 15, c = col & 15;
        float s = 0.f;
#pragma unroll
        for (int q = 0; q < 4; ++q) {
            float4 v0 = src[ch * 8 + q * 2];
            float4 v1 = src[ch * 8 + q * 2 + 1];
            float f[8] = {v0.x, v0.y, v0.z, v0.w, v1.x, v1.y, v1.z, v1.w};
            bf16x8 h, l;
#pragma unroll
            for (int j = 0; j < 8; ++j) {
                h[j] = (__bf16)f[j];
                l[j] = (__bf16)(f[j] - (float)h[j]);
                s += f[j] * f[j];
            }
            size_t off = ((size_t)(t8 * 8 + ch) * 16384) + (size_t)(g * 1024 + q * 256 + c * 16);
            *(bf16x8*)((char*)Eh + off) = h;
            *(bf16x8*)((char*)El + off) = l;
        }
        s += __shfl_xor(s, 1, 64);
        s += __shfl_xor(s, 2, 64);
        s += __shfl_xor(s, 4, 64);
        if (ch == 0) enorm[col] = s;
        return;
    }

    // transpose path
    float* A = out;
    int m  = bid & 15;
    int lt = bid >> 4;
    int l0 = lt * 16;
#pragma unroll
    for (int it = 0; it < 4; ++it) {
        int p   = tid + it * 256;
        int b   = p >> 6;
        int clo = (p >> 2) & 15;
        int l4  = p & 3;
        const float* g = ze + (size_t)b * ZE_CL + (size_t)(m * 16 + clo) * 2048 + l0 + 4 * l4;
        float4 v = *(const float4*)g;
        int jp = 17 * clo + b;
        T[(4 * l4 + 0) * 272 + jp] = v.x;
        T[(4 * l4 + 1) * 272 + jp] = v.y;
        T[(4 * l4 + 2) * 272 + jp] = v.z;
        T[(4 * l4 + 3) * 272 + jp] = v.w;
    }
    __syncthreads();
#pragma unroll
    for (int it = 0; it < 4; ++it) {
        int p  = tid + it * 256;
        int ll = p >> 6;
        int c4 = p & 63;
        int j0 = 4 * c4;
        int base = ll * 272 + 17 * (j0 >> 4) + (j0 & 15);
        float4 v;
        v.x = T[base + 0]; v.y = T[base + 1]; v.z = T[base + 2]; v.w = T[base + 3];
        int n = (l0 + ll) * 16 + m;
        *(float4*)(A + (size_t)n * DD + j0) = v;
        {
            float a0 = -2.f * v.x, a1 = -2.f * v.y, a2 = -2.f * v.z, a3 = -2.f * v.w;
            bf16x4 h, l;
            h[0] = (__bf16)a0; l[0] = (__bf16)(a0 - (float)h[0]);
            h[1] = (__bf16)a1; l[1] = (__bf16)(a1 - (float)h[1]);
            h[2] = (__bf16)a2; l[2] = (__bf16)(a2 - (float)h[2]);
            h[3] = (__bf16)a3; l[3] = (__bf16)(a3 - (float)h[3]);
            int bn = n >> 6, mi = (n >> 4) & 3, r = n & 15;
            int ch = j0 >> 5, q = (j0 >> 3) & 3, hb = (j0 & 7) * 2;
            size_t off = (size_t)bn * 32768 + (size_t)((mi * 8 + ch) * 1024 + q * 256 + r * 16 + hb);
            *(bf16x4*)((char*)Ah + off) = h;
            *(bf16x4*)((char*)Al + off) = l;
        }
    }
}

// ---------------- MFMA distance + top-2 argmin + fused epilogue ----------------
// 1024 blocks x 4 waves (256 thr). Block: 32 rows x 2048 cols (8 passes of 256).
// Wave: 32 rows x 64 cols via 2x4 frags of mfma_f32_16x16x32_bf16.
// A (32 KB) in LDS after one-time fill; B streams from global (E, L2-resident)
// with a per-block ROTATED (nt,ch) walk to avoid the all-blocks-same-chunk
// L2 hotspot. No in-loop barriers.
__global__ __launch_bounds__(256, 2) void vq_main_mfma(
    const __bf16* __restrict__ Ah, const __bf16* __restrict__ Al,
    const __bf16* __restrict__ Eh, const __bf16* __restrict__ El,
    const float* __restrict__ enorm, const float* __restrict__ emb,
    float* out, int* __restrict__ rcount, int* __restrict__ rlist)
{
    __shared__ __align__(16) char sA[32768];     // Ah slice [0,16K), Al slice [16K,32K)
    __shared__ float sRv[128], sR2[128];
    __shared__ int   sRi[128];
    __shared__ int   sIdx[32], sFlag[32];
    __shared__ float wsum[4];

    const int tid  = threadIdx.x;
    const int wv   = tid >> 6;        // 0..3
    const int lane = tid & 63;
    const int l15  = lane & 15;
    const int quad = lane >> 4;
    const int n0   = blockIdx.x * 32;
    const int bn   = blockIdx.x >> 1;          // 64-row image block
    const int miB  = (blockIdx.x & 1) * 2;     // which half (mi planes 0-1 / 2-3)
    // walk rotation: same-XCD blocks (bid = x mod 8) get distinct phases
    const int nt0  = (blockIdx.x >> 3) & 7;
    const int ch0  = (blockIdx.x >> 6) & 7;

    // one-time A -> LDS fill: 16KB hi + 16KB lo (wave-uniform base + lane*16)
    {
        const char* srcH = (const char*)Ah + (size_t)bn * 32768 + (size_t)miB * 8192;
        const char* srcL = (const char*)Al + (size_t)bn * 32768 + (size_t)miB * 8192;
#pragma unroll
        for (int it = 0; it < 4; ++it) {
            int off = (it * 4 + wv) * 1024;
            gld_lds16(srcH + off + lane * 16, sA + off);
            gld_lds16(srcL + off + lane * 16, sA + 16384 + off);
        }
    }

    // wave's B base: cells (wv*4+nj) of each 16KB ch-chunk, lane-linear
    const char* EhW = (const char*)Eh + (size_t)(wv * 4) * 1024 + (size_t)lane * 16;
    const char* ElW = (const char*)El + (size_t)(wv * 4) * 1024 + (size_t)lane * 16;
    const char* sAl16 = sA + (size_t)lane * 16;

    float v1[8], v2[8]; int i1[8];
#pragma unroll
    for (int s = 0; s < 8; ++s) { v1[s] = 3.4e38f; v2[s] = 3.4e38f; i1[s] = 0; }

    __syncthreads();   // A fill complete (drains vmcnt for global_load_lds)

    for (int ntc = 0; ntc < 8; ++ntc) {
        int nt = ntc + nt0; if (nt >= 8) nt -= 8;
        const char* EhT = EhW + (size_t)nt * 131072;
        const char* ElT = ElW + (size_t)nt * 131072;
        f32x4 acc[2][4];
#pragma unroll
        for (int a = 0; a < 2; ++a)
#pragma unroll
            for (int b = 0; b < 4; ++b) acc[a][b] = (f32x4){0.f, 0.f, 0.f, 0.f};

#pragma unroll 2
        for (int chc = 0; chc < 8; ++chc) {
            int ch = chc + ch0; if (ch >= 8) ch -= 8;
            bf16x8 ah[2], al[2], bh[4], bl[4];
#pragma unroll
            for (int nj = 0; nj < 4; ++nj) {
                size_t boff = (size_t)(ch * 16384 + nj * 1024);
                bh[nj] = *(const bf16x8*)(EhT + boff);
                bl[nj] = *(const bf16x8*)(ElT + boff);
            }
#pragma unroll
            for (int mi = 0; mi < 2; ++mi) {
                size_t off = (size_t)((mi * 8 + ch) * 1024);
                ah[mi] = *(const bf16x8*)(sAl16 + off);
                al[mi] = *(const bf16x8*)(sAl16 + 16384 + off);
            }
#pragma unroll
            for (int mi = 0; mi < 2; ++mi)
#pragma unroll
                for (int nj = 0; nj < 4; ++nj)
                    acc[mi][nj] = __builtin_amdgcn_mfma_f32_16x16x32_bf16(ah[mi], bh[nj], acc[mi][nj], 0, 0, 0);
#pragma unroll
            for (int mi = 0; mi < 2; ++mi)
#pragma unroll
                for (int nj = 0; nj < 4; ++nj)
                    acc[mi][nj] = __builtin_amdgcn_mfma_f32_16x16x32_bf16(ah[mi], bl[nj], acc[mi][nj], 0, 0, 0);
#pragma unroll
            for (int mi = 0; mi < 2; ++mi)
#pragma unroll
                for (int nj = 0; nj < 4; ++nj)
                    acc[mi][nj] = __builtin_amdgcn_mfma_f32_16x16x32_bf16(al[mi], bh[nj], acc[mi][nj], 0, 0, 0);
        }
        // fold N-pass into running top-2 (branchless; k uses the ACTUAL nt)
#pragma unroll
        for (int nj = 0; nj < 4; ++nj) {
            int k = nt * 256 + wv * 64 + nj * 16 + l15;
            float en = enorm[k];
#pragma unroll
            for (int mi = 0; mi < 2; ++mi)
#pragma unroll
                for (int r = 0; r < 4; ++r) {
                    float d = acc[mi][nj][r] + en;
                    int slot = mi * 4 + r;
                    float nv2 = fminf(v2[slot], fmaxf(v1[slot], d));
                    if (d < v1[slot]) i1[slot] = k;
                    v1[slot] = fminf(v1[slot], d);
                    v2[slot] = nv2;
                }
        }
    }

    // cross-lane top-2 merge over 16 lanes (rows fixed per quad)
#pragma unroll
    for (int slot = 0; slot < 8; ++slot) {
        float a1 = v1[slot], a2 = v2[slot];
        int ai = i1[slot];
#pragma unroll
        for (int m = 1; m < 16; m <<= 1) {
            float b1 = __shfl_xor(a1, m, 64);
            float b2 = __shfl_xor(a2, m, 64);
            int bi = __shfl_xor(ai, m, 64);
            float n2 = fminf(fminf(a2, b2), fmaxf(a1, b1));
            if (b1 < a1) ai = bi;
            a1 = fminf(a1, b1);
            a2 = n2;
        }
        if (l15 == 0) {
            int row = (slot >> 2) * 16 + quad * 4 + (slot & 3);   // 0..31
            sRv[row * 4 + wv] = a1;
            sR2[row * 4 + wv] = a2;
            sRi[row * 4 + wv] = ai;
        }
    }
    __syncthreads();
    if (tid < 32) {
        float a1 = sRv[tid * 4], a2 = sR2[tid * 4];
        int ai = sRi[tid * 4];
#pragma unroll
        for (int w2 = 1; w2 < 4; ++w2) {
            float b1 = sRv[tid * 4 + w2], b2 = sR2[tid * 4 + w2];
            int bi = sRi[tid * 4 + w2];
            float n2 = fminf(fminf(a2, b2), fmaxf(a1, b1));
            if (b1 < a1) ai = bi;
            a1 = fminf(a1, b1);
            a2 = n2;
        }
        int fg = (a2 - a1 < D2) ? 1 : 0;   // exact ties (gap 0) always flagged -> rescore
        sIdx[tid] = ai;
        sFlag[tid] = fg;
        out[IDX_OFF + n0 + tid] = (float)ai;
        if (fg) { int p = atomicAdd(rcount, 1); rlist[p] = n0 + tid; }
    }
    __syncthreads();

    // fused epilogue: quantize + loss for non-flagged rows (x fp32 still in out)
    float lacc = 0.f;
#pragma unroll
    for (int it = 0; it < 8; ++it) {
        int p = tid + it * 256;
        int r = p >> 6;             // 0..31, whole wave shares a row
        int c4 = p & 63;
        if (!sFlag[r]) {
            int k = sIdx[r];
            size_t off = (size_t)(n0 + r) * DD + 4 * c4;
            float4 q = *(const float4*)(emb + (size_t)k * DD + 4 * c4);
            float4 a = *(const float4*)(out + off);
            float dx = q.x - a.x, dy = q.y - a.y, dz = q.z - a.z, dw = q.w - a.w;
            lacc += dx * dx + dy * dy + dz * dz + dw * dw;
            *(float4*)(out + off) = q;
        }
    }
#pragma unroll
    for (int off = 32; off > 0; off >>= 1) lacc += __shfl_down(lacc, off, 64);
    if ((tid & 63) == 0) wsum[tid >> 6] = lacc;
    __syncthreads();
    if (tid == 0) {
        float bs = wsum[0] + wsum[1] + wsum[2] + wsum[3];
        atomicAdd(out + LOSS_OFF, bs * (1.25f / 8388608.0f));
    }
}

// ---------------- exact fp32 finalize of flagged rows ----------------
__global__ void vq_rescore(const float* __restrict__ emb, const float* __restrict__ enorm,
                           float* out, const int* __restrict__ rcount,
                           const int* __restrict__ rlist) {
    __shared__ float sX[256];
    __shared__ float sV[256];
    __shared__ int   sK[256];
    __shared__ float sP[256];
    int cnt = *rcount;
    int tid = threadIdx.x;
    for (int li = blockIdx.x; li < cnt; li += gridDim.x) {
        int row = rlist[li];
        __syncthreads();
        sX[tid] = out[(size_t)row * DD + tid];   // fp32 x (main skipped this row)
        __syncthreads();
        float bv = 3.4e38f; int bk = 0;
        for (int jj = 0; jj < 8; ++jj) {
            int k = jj * 256 + tid;   // ascending per thread: '<' keeps first
            const float4* e4 = (const float4*)(emb + (size_t)k * DD);
            float dot = 0.f;
#pragma unroll 8
            for (int d4 = 0; d4 < 64; ++d4) {
                float4 e = e4[d4];
                float4 x = *(const float4*)(sX + d4 * 4);
                dot += x.x * e.x + x.y * e.y + x.z * e.z + x.w * e.w;
            }
            float s = enorm[k] - 2.f * dot;
            if (s < bv) { bv = s; bk = k; }
        }
        sV[tid] = bv; sK[tid] = bk;
        __syncthreads();
#pragma unroll
        for (int s = 128; s > 0; s >>= 1) {
            if (tid < s) {
                float vo = sV[tid + s]; int ko = sK[tid + s];
                if (vo < sV[tid] || (vo == sV[tid] && ko < sK[tid])) { sV[tid] = vo; sK[tid] = ko; }
            }
            __syncthreads();
        }
        int k = sK[0];
        float x = sX[tid];
        float q = emb[(size_t)k * DD + tid];
        out[(size_t)row * DD + tid] = q;
        float d = q - x;
        sP[tid] = d * d;
        __syncthreads();
#pragma unroll
        for (int s = 128; s > 0; s >>= 1) {
            if (tid < s) sP[tid] += sP[tid + s];
            __syncthreads();
        }
        if (tid == 0) {
            out[IDX_OFF + row] = (float)k;
            atomicAdd(out + LOSS_OFF, sP[0] * (1.25f / 8388608.0f));
        }
    }
}

// ---------------- fallback path kernels (only if ws too small) ----------------
__global__ void vq_prep_emb(const float* __restrict__ emb, float* __restrict__ enorm,
                            __bf16* __restrict__ Eh, __bf16* __restrict__ El) {
    int tid = threadIdx.x;
    int col = blockIdx.x * 32 + (tid >> 3);
    int ch  = tid & 7;
    const float4* src = (const float4*)(emb + (size_t)col * DD);
    int t8 = col >> 8, g = (col >> 4) & 15, c = col & 15;
    float s = 0.f;
#pragma unroll
    for (int q = 0; q < 4; ++q) {
        float4 v0 = src[ch * 8 + q * 2];
        float4 v1 = src[ch * 8 + q * 2 + 1];
        float f[8] = {v0.x, v0.y, v0.z, v0.w, v1.x, v1.y, v1.z, v1.w};
        bf16x8 h, l;
#pragma unroll
        for (int j = 0; j < 8; ++j) {
            h[j] = (__bf16)f[j];
            l[j] = (__bf16)(f[j] - (float)h[j]);
            s += f[j] * f[j];
        }
        size_t off = ((size_t)(t8 * 8 + ch) * 16384) + (size_t)(g * 1024 + q * 256 + c * 16);
        *(bf16x8*)((char*)Eh + off) = h;
        *(bf16x8*)((char*)El + off) = l;
    }
    s += __shfl_xor(s, 1, 64);
    s += __shfl_xor(s, 2, 64);
    s += __shfl_xor(s, 4, 64);
    if (ch == 0) enorm[col] = s;
}

__global__ void vq_transpose_split(const float* __restrict__ ze, float* __restrict__ A,
                                   __bf16* __restrict__ Ah, __bf16* __restrict__ Al) {
    __shared__ float T[16 * 272];
    int tid = threadIdx.x;
    int m  = blockIdx.x & 15;
    int lt = blockIdx.x >> 4;
    int l0 = lt * 16;
#pragma unroll
    for (int it = 0; it < 4; ++it) {
        int p   = tid + it * 256;
        int b   = p >> 6;
        int clo = (p >> 2) & 15;
        int l4  = p & 3;
        const float* g = ze + (size_t)b * ZE_CL + (size_t)(m * 16 + clo) * 2048 + l0 + 4 * l4;
        float4 v = *(const float4*)g;
        int jp = 17 * clo + b;
        T[(4 * l4 + 0) * 272 + jp] = v.x;
        T[(4 * l4 + 1) * 272 + jp] = v.y;
        T[(4 * l4 + 2) * 272 + jp] = v.z;
        T[(4 * l4 + 3) * 272 + jp] = v.w;
    }
    __syncthreads();
#pragma unroll
    for (int it = 0; it < 4; ++it) {
        int p  = tid + it * 256;
        int ll = p >> 6;
        int c4 = p & 63;
        int j0 = 4 * c4;
        int base = ll * 272 + 17 * (j0 >> 4) + (j0 & 15);
        float4 v;
        v.x = T[base + 0]; v.y = T[base + 1]; v.z = T[base + 2]; v.w = T[base + 3];
        int n = (l0 + ll) * 16 + m;
        *(float4*)(A + (size_t)n * DD + j0) = v;
        if (Ah) {
            float a0 = -2.f * v.x, a1 = -2.f * v.y, a2 = -2.f * v.z, a3 = -2.f * v.w;
            bf16x4 h, l;
            h[0] = (__bf16)a0; l[0] = (__bf16)(a0 - (float)h[0]);
            h[1] = (__bf16)a1; l[1] = (__bf16)(a1 - (float)h[1]);
            h[2] = (__bf16)a2; l[2] = (__bf16)(a2 - (float)h[2]);
            h[3] = (__bf16)a3; l[3] = (__bf16)(a3 - (float)h[3]);
            int bn = n >> 6, mi = (n >> 4) & 3, r = n & 15;
            int ch = j0 >> 5, q = (j0 >> 3) & 3, hb = (j0 & 7) * 2;
            size_t off = (size_t)bn * 32768 + (size_t)((mi * 8 + ch) * 1024 + q * 256 + r * 16 + hb);
            *(bf16x4*)((char*)Ah + off) = h;
            *(bf16x4*)((char*)Al + off) = l;
        }
    }
}

__global__ __launch_bounds__(256, 2) void vq_main_f32(const float* __restrict__ emb,
                                                      const float* __restrict__ enorm,
                                                      float* out) {
    const int SA = 68, SE = 68;
    __shared__ float smem[64 * 68 + 64 * 68];
    __shared__ int   sIdx[64];
    __shared__ float wsum[4];
    float* sA = smem;
    float* sEb = smem + 64 * SA;
    float* redv = sEb;
    int*   redi = (int*)(sEb + 64 * 16);
    int tid = threadIdx.x;
    int n0 = blockIdx.x * 64;
    int rg = tid & 15;
    int kg = tid >> 4;
    float minv[4]; int mini[4];
#pragma unroll
    for (int i = 0; i < 4; ++i) { minv[i] = 3.4e38f; mini[i] = 0; }
    const float* A = out;
    for (int kt = 0; kt < KC / 64; ++kt) {
        int k0 = kt * 64;
        float acc[4][4];
#pragma unroll
        for (int i = 0; i < 4; ++i)
#pragma unroll
            for (int j = 0; j < 4; ++j) acc[i][j] = 0.f;
        for (int dc = 0; dc < 4; ++dc) {
            int d0 = dc * 64;
            __syncthreads();
#pragma unroll
            for (int it = 0; it < 4; ++it) {
                int p = tid + it * 256, r = p >> 4, c4 = p & 15;
                *(float4*)(sA + r * SA + 4 * c4) =
                    *(const float4*)(A + (size_t)(n0 + r) * DD + d0 + 4 * c4);
            }
#pragma unroll
            for (int it = 0; it < 4; ++it) {
                int p = tid + it * 256, r = p >> 4, c4 = p & 15;
                *(float4*)(sEb + r * SE + 4 * c4) =
                    *(const float4*)(emb + (size_t)(k0 + r) * DD + d0 + 4 * c4);
            }
            __syncthreads();
#pragma unroll
            for (int d4 = 0; d4 < 16; ++d4) {
                float4 av[4], ev[4];
#pragma unroll
                for (int i = 0; i < 4; ++i) av[i] = *(const float4*)(sA + (rg + 16 * i) * SA + 4 * d4);
#pragma unroll
                for (int j = 0; j < 4; ++j) ev[j] = *(const float4*)(sEb + (kg + 16 * j) * SE + 4 * d4);
#pragma unroll
                for (int i = 0; i < 4; ++i)
#pragma unroll
                    for (int j = 0; j < 4; ++j)
                        acc[i][j] += av[i].x * ev[j].x + av[i].y * ev[j].y +
                                     av[i].z * ev[j].z + av[i].w * ev[j].w;
            }
        }
#pragma unroll
        for (int j = 0; j < 4; ++j) {
            int k = k0 + kg + 16 * j;
            float en = enorm[k];
#pragma unroll
            for (int i = 0; i < 4; ++i) {
                float s = en - 2.f * acc[i][j];
                if (s < minv[i]) { minv[i] = s; mini[i] = k; }
            }
        }
    }
    __syncthreads();
#pragma unroll
    for (int i = 0; i < 4; ++i) {
        int r = rg + 16 * i;
        redv[r * 16 + kg] = minv[i];
        redi[r * 16 + kg] = mini[i];
    }
    __syncthreads();
    if (tid < 64) {
        float bv = redv[tid * 16]; int bi = redi[tid * 16];
        for (int t = 1; t < 16; ++t) {
            float v = redv[tid * 16 + t]; int ii = redi[tid * 16 + t];
            if (v < bv || (v == bv && ii < bi)) { bv = v; bi = ii; }
        }
        sIdx[tid] = bi;
        out[IDX_OFF + n0 + tid] = (float)bi;
    }
    __syncthreads();
    float lacc = 0.f;
#pragma unroll
    for (int it = 0; it < 16; ++it) {
        int p = tid + it * 256, r = p >> 6, c4 = p & 63;
        int k = sIdx[r];
        size_t off = (size_t)(n0 + r) * DD + 4 * c4;
        float4 q = *(const float4*)(emb + (size_t)k * DD + 4 * c4);
        float4 a = *(const float4*)(out + off);
        float dx = q.x - a.x, dy = q.y - a.y, dz = q.z - a.z, dw = q.w - a.w;
        lacc += dx * dx + dy * dy + dz * dz + dw * dw;
        *(float4*)(out + off) = q;
    }
#pragma unroll
    for (int off = 32; off > 0; off >>= 1) lacc += __shfl_down(lacc, off, 64);
    if ((tid & 63) == 0) wsum[tid >> 6] = lacc;
    __syncthreads();
    if (tid == 0) {
        float bs = wsum[0] + wsum[1] + wsum[2] + wsum[3];
        atomicAdd(out + LOSS_OFF, bs * (1.25f / 8388608.0f));
    }
}

extern "C" void kernel_launch(void* const* d_in, const int* in_sizes, int n_in,
                              void* d_out, int out_size, void* d_ws, size_t ws_size,
                              hipStream_t stream) {
    (void)in_sizes; (void)n_in; (void)out_size;
    const float* ze  = (const float*)d_in[0];
    const float* emb = (const float*)d_in[1];
    float* out = (float*)d_out;
    char*  ws  = (char*)d_ws;
    float* enorm = (float*)(ws + EN_OFF);

    if (ws_size >= (size_t)WS_NEED) {
        __bf16* Eh = (__bf16*)(ws + EH_OFF);
        __bf16* El = (__bf16*)(ws + EL_OFF);
        __bf16* Ah = (__bf16*)(ws + AH_OFF);
        __bf16* Al = (__bf16*)(ws + AL_OFF);
        int* rcount = (int*)(ws + CNT_OFF);
        int* rlist  = (int*)(ws + LST_OFF);
        vq_prep_all<<<2112, 256, 0, stream>>>(ze, emb, out, enorm, Eh, El, Ah, Al, rcount);
        vq_main_mfma<<<NROWS / 32, 256, 0, stream>>>(Ah, Al, Eh, El, enorm, emb, out, rcount, rlist);
        vq_rescore<<<512, 256, 0, stream>>>(emb, enorm, out, rcount, rlist);
    } else {
        // fallback: fp32 path (slow but correct)
        hipMemsetAsync((char*)d_out + (size_t)LOSS_OFF * 4, 0, 4, stream);
        vq_prep_emb<<<64, 256, 0, stream>>>(emb, enorm, (__bf16*)(ws + EH_OFF), (__bf16*)(ws + EH_OFF));
        vq_transpose_split<<<2048, 256, 0, stream>>>(ze, out, (__bf16*)0, (__bf16*)0);
        vq_main_f32<<<NROWS / 64, 256, 0, stream>>>(emb, enorm, out);
    }
}